// Round 7
// baseline (429.524 us; speedup 1.0000x reference)
//
#include <hip/hip_runtime.h>
#include <hip/hip_bf16.h>
#include <math.h>

typedef __attribute__((ext_vector_type(8))) short short8;
typedef __attribute__((ext_vector_type(16))) float f32x16;

#define MU_  0.1f
#define THR_ 0.01f

static __device__ inline short f2bf(float f) {
    __hip_bfloat16 h = __float2bfloat16(f);
    return *reinterpret_cast<short*>(&h);
}
static __device__ inline float bf2f(unsigned short u) {
    unsigned int x = ((unsigned int)u) << 16;
    return __builtin_bit_cast(float, x);
}

// ---------------------------------------------------------------------------
__global__ __launch_bounds__(256) void zero_kernel(float4* p, int n4) {
    int i = blockIdx.x * 256 + threadIdx.x;
    if (i < n4) p[i] = make_float4(0.f, 0.f, 0.f, 0.f);
}

// ---------------------------------------------------------------------------
// Normalize W; emit:
//  Wf2[t][chunk c][co][8] = Wn[co][(c*8+e)*9+t]      (fwd A, k-major slices
//      for coalesced LDS staging; logical ci order — matches B's chunk map)
//  Wt [t][ci][co ^ ((ci&7)<<3)] = Wn[co][ci*9+(8-t)] (conv_t A, gather layout)
// ---------------------------------------------------------------------------
__global__ __launch_bounds__(64) void wnorm_pack(
    const float* __restrict__ W, short* __restrict__ Wf2, short* __restrict__ Wt) {
    int co = blockIdx.x, ci = threadIdx.x;
    const float* wp = W + (co * 64 + ci) * 9;
    float v[9]; float s = 0.f;
#pragma unroll
    for (int t = 0; t < 9; ++t) { v[t] = wp[t]; s += v[t] * v[t]; }
#pragma unroll
    for (int off = 32; off; off >>= 1) s += __shfl_xor(s, off, 64);
    float inv = 1.0f / sqrtf(s + 1e-12f);
#pragma unroll
    for (int t = 0; t < 9; ++t) {
        Wf2[((t * 8 + (ci >> 3)) * 128 + co) * 8 + (ci & 7)] = f2bf(v[t] * inv);
        Wt[(t * 64 + ci) * 128 + (co ^ ((ci & 7) << 3))] = f2bf(v[8 - t] * inv);
    }
}

// ---------------------------------------------------------------------------
// Pack x (fp32 NCHW) -> Xp bf16 padded NHWC swizzled [n][58][68][64].
// ---------------------------------------------------------------------------
__global__ __launch_bounds__(256) void pack_x(
    const float* __restrict__ x, short* __restrict__ Xp) {
    __shared__ float lx[64 * 57];
    int row = blockIdx.x, n = blockIdx.y, tid = threadIdx.x;
    short* dst = Xp + ((size_t)(n * 58 + row) * 68) * 64;
    if (row >= 1 && row <= 56) {
        int h = row - 1;
        for (int j = tid; j < 64 * 56; j += 256) {
            int ci = j / 56, w = j - ci * 56;
            lx[ci * 57 + w] = x[((size_t)(n * 64 + ci)) * 3136 + h * 56 + w];
        }
        __syncthreads();
        for (int j = tid; j < 68 * 64; j += 256) {
            int s = j >> 6, ci = j & 63;
            float val = (s >= 2 && s < 58) ? lx[ci * 57 + (s - 2)] : 0.f;
            dst[(s << 6) + (ci ^ ((s & 7) << 3))] = f2bf(val);
        }
    } else {
        for (int j = tid; j < 68 * 64; j += 256) dst[j] = 0;
    }
}

// ---------------------------------------------------------------------------
// Forward conv 64->128 implicit GEMM, full 128 co per block (512 thr, 8 waves
// = 8 tiles 32co x 32px). A-slices (16 KB/t) staged coalesced into ping-pong
// LDS buffers; fragments read as contiguous ds_read_b128 (no global gathers).
// grid=(56 rows, 16 n). FISTA state in bf16 swz NHWC (Yp, Cp).
// mode 0: c=shrink(MU*acc); y=cp=c
// mode 1: c=shrink(y_old+MU*acc); y=c+beta*(c-cp_old); cp=c
// mode 2: out=shrink(y_old+MU*acc)  (fp32 NCHW, no state writes)
// ---------------------------------------------------------------------------
__global__ __launch_bounds__(512, 4) void conv_fwd(
    const short* __restrict__ inp,   // [n][58][68][64] bf16 swz (Xp or Rp)
    const short* __restrict__ Wf2,   // [9][8][128][8] bf16 (k-major slices)
    short* __restrict__ Yp,          // [n][58][68][128] bf16 swz (y state)
    short* __restrict__ Cp,          // [n][58][68][128] bf16 swz (c_prev)
    float* __restrict__ outp, int mode, float beta) {
    __shared__ __align__(16) short smem[29440];  // 58880 B
    short* xs = smem;                 // B-tile: 13056 shorts (26112 B)
    short* a0 = smem + 13056;         // A slice buf 0: 8192 shorts
    short* a1 = smem + 21248;         // A slice buf 1: 8192 shorts
    const int r = blockIdx.x + 1, n = blockIdx.y, tid = threadIdx.x;

    // old-state prefetch (coalesced short8; full 128-ch row; 896 items)
    const size_t prow = ((size_t)(n * 58 + r) * 68) * 128;
    short8 yold8[2], cold8[2];
    int pvv[2], pg[2]; bool pok[2];
#pragma unroll
    for (int k = 0; k < 2; ++k) {
        int item = tid + k * 512;
        pok[k] = item < 896;
        pvv[k] = item >> 4; pg[k] = item & 15;
        if (mode != 0 && pok[k]) {
            int s = pvv[k] + 2;
            size_t off = prow + (size_t)s * 128 + 8 * (pg[k] ^ (s & 7));
            yold8[k] = *(const short8*)(Yp + off);
            if (mode == 1) cold8[k] = *(const short8*)(Cp + off);
        }
    }
    {   // stage B: 3 contiguous input rows (1632 short8)
        const short8* src = (const short8*)(inp + ((size_t)(n * 58 + (r - 1)) * 68) * 64);
        short8* d = (short8*)xs;
        for (int j = tid; j < 1632; j += 512) d[j] = src[j];
    }
    {   // stage A[0] (1024 short8)
        const short8* asrc = (const short8*)Wf2;
        short8 s0 = asrc[tid], s1 = asrc[tid + 512];
        ((short8*)a0)[tid] = s0; ((short8*)a0)[tid + 512] = s1;
    }
    __syncthreads();

    const int lane = tid & 63, wid = tid >> 6, qh = lane >> 5, v0 = lane & 31;
    const int cot = wid & 3, ph = wid >> 2;
    const int co = cot * 32 + v0;     // output channel (A row)
    const int v  = ph * 32 + v0;      // pixel within row
    const int h  = r - 1;

    int bg[3][4];
#pragma unroll
    for (int dw = 0; dw < 3; ++dw) {
        int key = (v0 + dw + 1) & 7;
#pragma unroll
        for (int s = 0; s < 4; ++s) bg[dw][s] = 8 * ((2 * s + qh) ^ key);
    }

    f32x16 acc;
#pragma unroll
    for (int i = 0; i < 16; ++i) acc[i] = 0.f;

#pragma unroll
    for (int t = 0; t < 9; ++t) {
        short8 st0, st1;
        if (t < 8) {   // coalesced global loads of next A slice (ride under MFMA)
            const short8* asrc = (const short8*)(Wf2 + (t + 1) * 8192);
            st0 = asrc[tid]; st1 = asrc[tid + 512];
        }
        const int dh = t / 3, dw = t % 3;
        const int b_base = (dh * 68 + (v + dw + 1)) * 64;
        const short* abuf = (t & 1) ? a1 : a0;
#pragma unroll
        for (int s = 0; s < 4; ++s) {
            short8 aF = *(const short8*)(abuf + ((2 * s + qh) * 128 + co) * 8);
            short8 bF = *(const short8*)(xs + b_base + bg[dw][s]);
            acc = __builtin_amdgcn_mfma_f32_32x32x16_bf16(aF, bF, acc, 0, 0, 0);
        }
        if (t < 8) {
            short8* ad = (short8*)((t & 1) ? a0 : a1);
            ad[tid] = st0; ad[tid + 512] = st1;
        }
        __syncthreads();
    }

    // ---- epilogue (smem dead; reuse as [64 px][136 ch] transpose bufs) ----
    short* tb_y = smem;               // 8704 shorts
    short* tb_c = smem + 8704;        // 8704 shorts
    if (mode != 0) {                  // dump prefetched old state to LDS
#pragma unroll
        for (int k = 0; k < 2; ++k) if (pok[k]) {
            int o = pvv[k] * 136 + 8 * (pg[k] ^ (pvv[k] & 3));
            *(short8*)(tb_y + o) = yold8[k];
            if (mode == 1) *(short8*)(tb_c + o) = cold8[k];
        }
    }
    __syncthreads();
#pragma unroll
    for (int reg = 0; reg < 16; ++reg) {
        const int crl = (reg & 3) + 8 * (reg >> 2) + 4 * qh;   // 0..31
        const int lch = cot * 32 + crl;                        // 0..127
        const int slot = v * 136 + (lch ^ ((v & 3) << 3));
        const float a = acc[reg];
        if (mode == 0) {
            float c = fmaxf(MU_ * a - THR_, 0.f);
            short cb16 = f2bf(c);
            tb_y[slot] = cb16;
            tb_c[slot] = cb16;
        } else if (mode == 1) {
            float yold = bf2f((unsigned short)tb_y[slot]);
            float cold = bf2f((unsigned short)tb_c[slot]);
            float c = fmaxf(yold + MU_ * a - THR_, 0.f);
            float ynew = c + beta * (c - cold);
            tb_y[slot] = f2bf(ynew);
            tb_c[slot] = f2bf(c);
        } else {
            if (v < 56) {
                float yold = bf2f((unsigned short)tb_y[slot]);
                float c = fmaxf(yold + MU_ * a - THR_, 0.f);
                outp[((size_t)(n * 128 + lch)) * 3136 + h * 56 + v] = c;
            }
        }
    }
    if (mode != 2) {                  // contiguous coalesced state writeback
        __syncthreads();
        for (int item = tid; item < 896; item += 512) {
            int vv = item >> 4, g = item & 15;
            int so = vv * 136 + 8 * (g ^ (vv & 3));
            short8 yv = *(const short8*)(tb_y + so);
            short8 cv = *(const short8*)(tb_c + so);
            int s = vv + 2;
            size_t off = prow + (size_t)s * 128 + 8 * (g ^ (s & 7));
            *(short8*)(Yp + off) = yv;
            *(short8*)(Cp + off) = cv;
        }
    }
}

// ---------------------------------------------------------------------------
// Transpose conv 128->64 implicit GEMM, fused residual r = x - D^T y with
// x read from bf16 Xp (same layout as Rp). grid=(56,16), block=256.
// (unchanged from round 6 — control for this round's conv_fwd experiment)
// ---------------------------------------------------------------------------
__global__ __launch_bounds__(256) void conv_t(
    const short* __restrict__ Ypb,   // [n][58][68][128] bf16 swz
    const short* __restrict__ Wt,    // [9][64][128] bf16 swz
    const short* __restrict__ Xp,    // [n][58][68][64] bf16 swz
    short* __restrict__ Rp) {        // [n][58][68][64] bf16 swz
    __shared__ short ys[3 * 68 * 128];   // 52224 B; reused post-MFMA
    const int r = blockIdx.x + 1, n = blockIdx.y, tid = threadIdx.x;
    {
        const short8* src = (const short8*)(Ypb + ((size_t)(n * 58 + (r - 1)) * 68) * 128);
        short8* d = (short8*)ys;
        for (int j = tid; j < 3264; j += 256) d[j] = src[j];
    }

    const size_t prow = ((size_t)(n * 58 + r) * 68) * 64;
    short8 xold8[2];
    int pvv[2], pg[2]; bool pok[2];
#pragma unroll
    for (int k = 0; k < 2; ++k) {
        int item = tid + k * 256;
        pok[k] = item < 448;
        pvv[k] = item >> 3; pg[k] = item & 7;
        if (pok[k]) {
            int s = pvv[k] + 2;
            xold8[k] = *(const short8*)(Xp + prow + (size_t)s * 64 + 8 * (pg[k] ^ (s & 7)));
        }
    }
    __syncthreads();

    const int lane = tid & 63, wid = tid >> 6, qh = lane >> 5, l31 = lane & 31;
    const int cib = (wid & 1) * 32, vb = (wid >> 1) * 32;
    const int ci = cib + l31;
    const int v = vb + l31;

    int goffA[8], bg[3][8];
#pragma unroll
    for (int s = 0; s < 8; ++s) goffA[s] = 8 * ((2 * s + qh) ^ (ci & 7));
#pragma unroll
    for (int dw = 0; dw < 3; ++dw) {
        int key = (l31 + dw + 1) & 7;    // vb % 8 == 0
#pragma unroll
        for (int s = 0; s < 8; ++s) bg[dw][s] = 8 * ((2 * s + qh) ^ key);
    }
    const short* wbase = Wt + ci * 128;

    f32x16 acc;
#pragma unroll
    for (int i = 0; i < 16; ++i) acc[i] = 0.f;

    short8 Af[2][8];
#pragma unroll
    for (int s = 0; s < 8; ++s) Af[0][s] = *(const short8*)(wbase + goffA[s]);

#pragma unroll
    for (int t = 0; t < 9; ++t) {
        if (t + 1 < 9) {
#pragma unroll
            for (int s = 0; s < 8; ++s)
                Af[(t + 1) & 1][s] = *(const short8*)(wbase + (t + 1) * 8192 + goffA[s]);
        }
        const int dh = t / 3, dw = t % 3;
        const int b_base = (dh * 68 + (v + dw + 1)) * 128;
#pragma unroll
        for (int s = 0; s < 8; ++s) {
            short8 bv = *(const short8*)(ys + b_base + bg[dw][s]);
            acc = __builtin_amdgcn_mfma_f32_32x32x16_bf16(Af[t & 1][s], bv, acc, 0, 0, 0);
        }
    }

    __syncthreads();                 // ys dead
    short* tb = ys;                  // [64 px][72 ch], XOR-swizzled by (v&3)
#pragma unroll
    for (int k = 0; k < 2; ++k) if (pok[k]) {
        *(short8*)(tb + pvv[k] * 72 + 8 * (pg[k] ^ (pvv[k] & 3))) = xold8[k];
    }
    __syncthreads();
#pragma unroll
    for (int reg = 0; reg < 16; ++reg) {
        const int cir = cib + (reg & 3) + 8 * (reg >> 2) + 4 * qh;
        const int slot = v * 72 + (cir ^ ((v & 3) << 3));
        float xo = bf2f((unsigned short)tb[slot]);
        tb[slot] = f2bf(xo - acc[reg]);
    }
    __syncthreads();
    short* rdst = Rp + prow;
    for (int item = tid; item < 448; item += 256) {
        int vv = item >> 3, g = item & 7;
        short8 val = *(const short8*)(tb + vv * 72 + 8 * (g ^ (vv & 3)));
        int s = vv + 2;
        *(short8*)(rdst + (size_t)s * 64 + 8 * (g ^ (s & 7))) = val;
    }
}

// ---------------------------------------------------------------------------
extern "C" void kernel_launch(void* const* d_in, const int* in_sizes, int n_in,
                              void* d_out, int out_size, void* d_ws, size_t ws_size,
                              hipStream_t stream) {
    const float* x = (const float*)d_in[0];   // [16,64,56,56] fp32
    const float* W = (const float*)d_in[1];   // [128,64,3,3]  fp32
    float* out = (float*)d_out;               // [16,128,56,56] fp32

    // ws layout (all bf16): Xp | Rp | Yp | Cp | Wf2 | Wt  (~49 MB)
    const size_t XPN = (size_t)16 * 58 * 68 * 64;   // 4,038,656
    const size_t YPN = 2 * XPN;                      // 8,077,312
    short* Xp = (short*)d_ws;
    short* Rp = Xp + XPN;
    short* Yp = Rp + XPN;
    short* Cp = Yp + YPN;
    short* Wf2 = Cp + YPN;                // 73728 shorts
    short* Wt  = Wf2 + 73728;             // 73728 shorts

    // zero Rp+Yp (contiguous) so pad regions are 0 under ws re-poisoning
    const int n4 = (int)((XPN + YPN) * 2 / 16);
    hipLaunchKernelGGL(zero_kernel, dim3((n4 + 255) / 256), dim3(256), 0, stream,
                       (float4*)Rp, n4);
    hipLaunchKernelGGL(wnorm_pack, dim3(128), dim3(64), 0, stream, W, Wf2, Wt);
    hipLaunchKernelGGL(pack_x, dim3(58, 16), dim3(256), 0, stream, x, Xp);

    dim3 gf(56, 16), gt(56, 16);
    // it0: c = shrink(MU * conv(x)); y = cp = c
    hipLaunchKernelGGL(conv_fwd, gf, dim3(512), 0, stream, Xp, Wf2, Yp, Cp,
                       (float*)nullptr, 0, 0.f);
    double t = 1.0;
    for (int it = 1; it <= 5; ++it) {
        hipLaunchKernelGGL(conv_t, gt, dim3(256), 0, stream, Yp, Wt, Xp, Rp);
        double tn = (1.0 + sqrt(1.0 + 4.0 * t * t)) / 2.0;
        float beta = (float)((t - 1.0) / tn);
        hipLaunchKernelGGL(conv_fwd, gf, dim3(512), 0, stream, Rp, Wf2, Yp, Cp,
                           (it == 5) ? out : (float*)nullptr, (it == 5) ? 2 : 1,
                           beta);
        t = tn;
    }
}

// Round 8
// 372.403 us; speedup vs baseline: 1.1534x; 1.1534x over previous
//
#include <hip/hip_runtime.h>
#include <hip/hip_bf16.h>
#include <math.h>

typedef __attribute__((ext_vector_type(8))) short short8;
typedef __attribute__((ext_vector_type(4))) float f32x4;

#define MU_  0.1f
#define THR_ 0.01f

static __device__ inline short f2bf(float f) {
    __hip_bfloat16 h = __float2bfloat16(f);
    return *reinterpret_cast<short*>(&h);
}
static __device__ inline float bf2f(unsigned short u) {
    unsigned int x = ((unsigned int)u) << 16;
    return __builtin_bit_cast(float, x);
}

// ---------------------------------------------------------------------------
__global__ __launch_bounds__(256) void zero_kernel(float4* p, int n4) {
    int i = blockIdx.x * 256 + threadIdx.x;
    if (i < n4) p[i] = make_float4(0.f, 0.f, 0.f, 0.f);
}

// ---------------------------------------------------------------------------
// Normalize W; emit k-major chunked GEMM layouts (coalesced A register loads):
//  fwd:    k = t*64 + ci;  Wf2[t][ci>>3][co][ci&7]  = Wn[co][ci*9+t]
//  conv_t: k = t*128 + co; Wt2[t][co>>3][ci][co&7]  = Wn[co][ci*9+(8-t)]
// ---------------------------------------------------------------------------
__global__ __launch_bounds__(64) void wnorm_pack(
    const float* __restrict__ W, short* __restrict__ Wf2, short* __restrict__ Wt2) {
    int co = blockIdx.x, ci = threadIdx.x;
    const float* wp = W + (co * 64 + ci) * 9;
    float v[9]; float s = 0.f;
#pragma unroll
    for (int t = 0; t < 9; ++t) { v[t] = wp[t]; s += v[t] * v[t]; }
#pragma unroll
    for (int off = 32; off; off >>= 1) s += __shfl_xor(s, off, 64);
    float inv = 1.0f / sqrtf(s + 1e-12f);
#pragma unroll
    for (int t = 0; t < 9; ++t) {
        Wf2[((t * 8 + (ci >> 3)) * 128 + co) * 8 + (ci & 7)] = f2bf(v[t] * inv);
        Wt2[((t * 16 + (co >> 3)) * 64 + ci) * 8 + (co & 7)] = f2bf(v[8 - t] * inv);
    }
}

// ---------------------------------------------------------------------------
// Pack x (fp32 NCHW) -> Xp bf16 padded NHWC swizzled [n][58][68][64].
// ---------------------------------------------------------------------------
__global__ __launch_bounds__(256) void pack_x(
    const float* __restrict__ x, short* __restrict__ Xp) {
    __shared__ float lx[64 * 57];
    int row = blockIdx.x, n = blockIdx.y, tid = threadIdx.x;
    short* dst = Xp + ((size_t)(n * 58 + row) * 68) * 64;
    if (row >= 1 && row <= 56) {
        int h = row - 1;
        for (int j = tid; j < 64 * 56; j += 256) {
            int ci = j / 56, w = j - ci * 56;
            lx[ci * 57 + w] = x[((size_t)(n * 64 + ci)) * 3136 + h * 56 + w];
        }
        __syncthreads();
        for (int j = tid; j < 68 * 64; j += 256) {
            int s = j >> 6, ci = j & 63;
            float val = (s >= 2 && s < 58) ? lx[ci * 57 + (s - 2)] : 0.f;
            dst[(s << 6) + (ci ^ ((s & 7) << 3))] = f2bf(val);
        }
    } else {
        for (int j = tid; j < 68 * 64; j += 256) dst[j] = 0;
    }
}

// ---------------------------------------------------------------------------
// Forward conv 64->128, 16x16x32 MFMA, A register-resident (18 frags/lane),
// B in LDS with +8B row pad (72 shorts/row) to kill bank aliasing.
// grid=(56 rows, 2 co-halves, 16 n), block=256 (4 waves = 4 co-tiles of 16,
// each wave covers 64 px as 4 tiles of 16). No in-loop globals/barriers.
// mode 0: c=shrink(MU*acc); y=cp=c
// mode 1: c=shrink(y_old+MU*acc); y=c+beta*(c-cp_old); cp=c
// mode 2: out=shrink(y_old+MU*acc) (fp32 NCHW, no state writes)
// ---------------------------------------------------------------------------
__global__ __launch_bounds__(256) void conv_fwd(
    const short* __restrict__ inp,   // [n][58][68][64] bf16 swz (Xp or Rp)
    const short* __restrict__ Wf2,   // [9][8][128][8] bf16 k-major chunks
    short* __restrict__ Yp,          // [n][58][68][128] bf16 swz (y state)
    short* __restrict__ Cp,          // [n][58][68][128] bf16 swz (c_prev)
    float* __restrict__ outp, int mode, float beta) {
    __shared__ __align__(16) short smem[14688];   // 204 rows x 72 shorts
    const int r = blockIdx.x + 1, cb = blockIdx.y, n = blockIdx.z, tid = threadIdx.x;
    {   // stage B: 3 input rows, 64-short global rows -> 72-short LDS rows
        const short8* src = (const short8*)(inp + ((size_t)(n * 58 + (r - 1)) * 68) * 64);
        for (int j = tid; j < 1632; j += 256) {
            int srow = j >> 3, w = j & 7;
            *(short8*)(smem + srow * 72 + w * 8) = src[j];
        }
    }
    const int lane = tid & 63, ct = tid >> 6, quad = lane >> 4, l15 = lane & 15;
    const int co = cb * 64 + ct * 16 + l15;

    short8 Areg[18];                 // A[m=l15][k]: k frag f: t=f>>1, half=f&1
#pragma unroll
    for (int f = 0; f < 18; ++f) {
        int t = f >> 1, half = f & 1;
        Areg[f] = *(const short8*)(Wf2 + ((size_t)((t * 8 + half * 4 + quad) * 128 + co)) * 8);
    }
    __syncthreads();

    f32x4 acc[4];
#pragma unroll
    for (int pt = 0; pt < 4; ++pt) acc[pt] = (f32x4){0.f, 0.f, 0.f, 0.f};

#pragma unroll
    for (int f = 0; f < 18; ++f) {
        const int t = f >> 1, half = f & 1;
        const int dh = t / 3, dw = t % 3;
        const int u = l15 + dw + 1;               // col for px-tile 0
        const int phys = (half * 4 + quad) ^ (u & 7);
        const int base = (dh * 68 + u) * 72 + phys * 8;
#pragma unroll
        for (int pt = 0; pt < 4; ++pt) {
            short8 bv = *(const short8*)(smem + base + pt * 1152);  // +16 rows
            acc[pt] = __builtin_amdgcn_mfma_f32_16x16x32_bf16(Areg[f], bv, acc[pt], 0, 0, 0);
        }
    }

    // ---- epilogue: state bounce via LDS (smem dead) ----
    __syncthreads();
    short* tb_y = smem;              // [64 px][72 ch-half]
    short* tb_c = smem + 4608;
    const size_t prow = ((size_t)(n * 58 + r) * 68) * 128;
    if (mode != 0) {
        for (int item = tid; item < 448; item += 256) {
            int vv = item >> 3, g = item & 7;
            int s = vv + 2;
            size_t off = prow + (size_t)s * 128 + 8 * ((g + 8 * cb) ^ (s & 7));
            int o = vv * 72 + 8 * (g ^ (vv & 3));
            *(short8*)(tb_y + o) = *(const short8*)(Yp + off);
            if (mode == 1) *(short8*)(tb_c + o) = *(const short8*)(Cp + off);
        }
    }
    __syncthreads();
    const int h = r - 1;
#pragma unroll
    for (int pt = 0; pt < 4; ++pt) {
        const int px = pt * 16 + l15;
#pragma unroll
        for (int reg = 0; reg < 4; ++reg) {
            const int lch = ct * 16 + quad * 4 + reg;      // 0..63 (half-local)
            const int slot = px * 72 + (lch ^ ((px & 3) << 3));
            const float a = acc[pt][reg];
            if (mode == 0) {
                float c = fmaxf(MU_ * a - THR_, 0.f);
                short cb16 = f2bf(c);
                tb_y[slot] = cb16;
                tb_c[slot] = cb16;
            } else if (mode == 1) {
                float yold = bf2f((unsigned short)tb_y[slot]);
                float cold = bf2f((unsigned short)tb_c[slot]);
                float c = fmaxf(yold + MU_ * a - THR_, 0.f);
                tb_y[slot] = f2bf(c + beta * (c - cold));
                tb_c[slot] = f2bf(c);
            } else {
                if (px < 56) {
                    float yold = bf2f((unsigned short)tb_y[slot]);
                    float c = fmaxf(yold + MU_ * a - THR_, 0.f);
                    outp[((size_t)(n * 128 + cb * 64 + lch)) * 3136 + h * 56 + px] = c;
                }
            }
        }
    }
    if (mode != 2) {
        __syncthreads();
        for (int item = tid; item < 448; item += 256) {
            int vv = item >> 3, g = item & 7;
            int so = vv * 72 + 8 * (g ^ (vv & 3));
            short8 yv = *(const short8*)(tb_y + so);
            short8 cv = *(const short8*)(tb_c + so);
            int s = vv + 2;
            size_t off = prow + (size_t)s * 128 + 8 * ((g + 8 * cb) ^ (s & 7));
            *(short8*)(Yp + off) = yv;
            *(short8*)(Cp + off) = cv;
        }
    }
}

// ---------------------------------------------------------------------------
// Transpose conv 128->64, 16x16x32 MFMA, A register-resident per co-half
// pass (two passes over K, restage B chunk-half between). Fused residual
// r = x - D^T y with x from bf16 Xp. grid=(56,16), block=256.
// ---------------------------------------------------------------------------
__global__ __launch_bounds__(256) void conv_t(
    const short* __restrict__ Ypb,   // [n][58][68][128] bf16 swz
    const short* __restrict__ Wt2,   // [9][16][64][8] bf16 k-major chunks
    const short* __restrict__ Xp,    // [n][58][68][64] bf16 swz
    short* __restrict__ Rp) {        // [n][58][68][64] bf16 swz
    __shared__ __align__(16) short smem[14688];   // 204 rows x 72 shorts
    const int r = blockIdx.x + 1, n = blockIdx.y, tid = threadIdx.x;
    const int lane = tid & 63, ct = tid >> 6, quad = lane >> 4, l15 = lane & 15;
    const int ci = ct * 16 + l15;
    const short8* src = (const short8*)(Ypb + ((size_t)(n * 58 + (r - 1)) * 68) * 128);

    f32x4 acc[4];
#pragma unroll
    for (int pt = 0; pt < 4; ++pt) acc[pt] = (f32x4){0.f, 0.f, 0.f, 0.f};

#pragma unroll
    for (int p = 0; p < 2; ++p) {
        if (p) __syncthreads();      // prior pass's B reads complete
        // stage physical chunk-half p of each row (contig 128 B per 256 B row)
        for (int j = tid; j < 1632; j += 256) {
            int srow = j >> 3, w = j & 7;
            *(short8*)(smem + srow * 72 + w * 8) = src[srow * 16 + p * 8 + w];
        }
        short8 Areg[18];             // k frag f: t=f>>1, sub=p*2+(f&1)
#pragma unroll
        for (int f = 0; f < 18; ++f) {
            int t = f >> 1, sh = f & 1;
            Areg[f] = *(const short8*)(Wt2 +
                ((size_t)((t * 16 + (p * 2 + sh) * 4 + quad) * 64 + ci)) * 8);
        }
        __syncthreads();
#pragma unroll
        for (int f = 0; f < 18; ++f) {
            const int t = f >> 1, sh = f & 1;
            const int dh = t / 3, dw = t % 3;
            const int u = l15 + dw + 1;
            const int phys = (sh * 4 + quad) ^ (u & 7);
            const int base = (dh * 68 + u) * 72 + phys * 8;
#pragma unroll
            for (int pt = 0; pt < 4; ++pt) {
                short8 bv = *(const short8*)(smem + base + pt * 1152);
                acc[pt] = __builtin_amdgcn_mfma_f32_16x16x32_bf16(Areg[f], bv, acc[pt], 0, 0, 0);
            }
        }
    }

    // ---- epilogue: r = x - acc via LDS bounce ----
    __syncthreads();
    short* tb = smem;                // [64 px][72 ch]
    const size_t prow = ((size_t)(n * 58 + r) * 68) * 64;
    for (int item = tid; item < 448; item += 256) {
        int vv = item >> 3, g = item & 7;
        int s = vv + 2;
        *(short8*)(tb + vv * 72 + 8 * (g ^ (vv & 3))) =
            *(const short8*)(Xp + prow + (size_t)s * 64 + 8 * (g ^ (s & 7)));
    }
    __syncthreads();
#pragma unroll
    for (int pt = 0; pt < 4; ++pt) {
        const int px = pt * 16 + l15;
#pragma unroll
        for (int reg = 0; reg < 4; ++reg) {
            const int cir = ct * 16 + quad * 4 + reg;
            const int slot = px * 72 + (cir ^ ((px & 3) << 3));
            float xo = bf2f((unsigned short)tb[slot]);
            tb[slot] = f2bf(xo - acc[pt][reg]);
        }
    }
    __syncthreads();
    for (int item = tid; item < 448; item += 256) {
        int vv = item >> 3, g = item & 7;
        short8 val = *(const short8*)(tb + vv * 72 + 8 * (g ^ (vv & 3)));
        int s = vv + 2;
        *(short8*)(Rp + prow + (size_t)s * 64 + 8 * (g ^ (s & 7))) = val;
    }
}

// ---------------------------------------------------------------------------
extern "C" void kernel_launch(void* const* d_in, const int* in_sizes, int n_in,
                              void* d_out, int out_size, void* d_ws, size_t ws_size,
                              hipStream_t stream) {
    const float* x = (const float*)d_in[0];   // [16,64,56,56] fp32
    const float* W = (const float*)d_in[1];   // [128,64,3,3]  fp32
    float* out = (float*)d_out;               // [16,128,56,56] fp32

    // ws layout (all bf16): Xp | Rp | Yp | Cp | Wf2 | Wt2  (~49 MB)
    const size_t XPN = (size_t)16 * 58 * 68 * 64;   // 4,038,656
    const size_t YPN = 2 * XPN;                      // 8,077,312
    short* Xp = (short*)d_ws;
    short* Rp = Xp + XPN;
    short* Yp = Rp + XPN;
    short* Cp = Yp + YPN;
    short* Wf2 = Cp + YPN;                // 73728 shorts
    short* Wt2 = Wf2 + 73728;             // 73728 shorts

    // zero Rp+Yp (contiguous) so pad regions are 0 under ws re-poisoning
    const int n4 = (int)((XPN + YPN) * 2 / 16);
    hipLaunchKernelGGL(zero_kernel, dim3((n4 + 255) / 256), dim3(256), 0, stream,
                       (float4*)Rp, n4);
    hipLaunchKernelGGL(wnorm_pack, dim3(128), dim3(64), 0, stream, W, Wf2, Wt2);
    hipLaunchKernelGGL(pack_x, dim3(58, 16), dim3(256), 0, stream, x, Xp);

    dim3 gf(56, 2, 16), gt(56, 16), b(256, 1, 1);
    // it0: c = shrink(MU * conv(x)); y = cp = c
    hipLaunchKernelGGL(conv_fwd, gf, b, 0, stream, Xp, Wf2, Yp, Cp,
                       (float*)nullptr, 0, 0.f);
    double t = 1.0;
    for (int it = 1; it <= 5; ++it) {
        hipLaunchKernelGGL(conv_t, gt, b, 0, stream, Yp, Wt2, Xp, Rp);
        double tn = (1.0 + sqrt(1.0 + 4.0 * t * t)) / 2.0;
        float beta = (float)((t - 1.0) / tn);
        hipLaunchKernelGGL(conv_fwd, gf, b, 0, stream, Rp, Wf2, Yp, Cp,
                           (it == 5) ? out : (float*)nullptr, (it == 5) ? 2 : 1,
                           beta);
        t = tn;
    }
}